// Round 1
// baseline (313.120 us; speedup 1.0000x reference)
//
#include <hip/hip_runtime.h>
#include <hip/hip_bf16.h>

typedef __bf16 bf16x8 __attribute__((ext_vector_type(8)));
typedef float  float4v __attribute__((ext_vector_type(4)));
typedef unsigned short u16;
typedef u16 u16x4 __attribute__((ext_vector_type(4)));

#define NB 32
#define NT 2048
#define ND 512
#define NU 512
#define APITCH 40   // 32 + 8 pad (u16 units): 80B row stride -> 2-way LDS aliasing (free)

__device__ __forceinline__ u16 f2bf(float f) {
    union { float f; unsigned u; } v; v.f = f;
    unsigned u = v.u;
    return (u16)((u + 0x7fffu + ((u >> 16) & 1u)) >> 16);  // RNE
}

__device__ __forceinline__ float fast_tanh(float x) {
    // tanh(x) = 2/(1+exp(-2x)) - 1 ; saturates correctly at +/-inf of expf
    float e = __expf(-2.f * x);
    return 2.f / (1.f + e) - 1.f;
}

// ---- W1 [D,U] fp32 -> W1^T [U,D] bf16 --------------------------------------
__global__ void k_w1t(const float* __restrict__ W1, u16* __restrict__ w1t) {
    __shared__ u16 tile[32][33];
    int bd = (blockIdx.x & 15) * 32;
    int bu = (blockIdx.x >> 4) * 32;
    int tx = threadIdx.x & 31, ty = threadIdx.x >> 5;  // ty 0..7
    #pragma unroll
    for (int i = 0; i < 4; ++i) {
        int d = bd + ty + i * 8;
        tile[ty + i * 8][tx] = f2bf(W1[d * NU + bu + tx]);
    }
    __syncthreads();
    #pragma unroll
    for (int i = 0; i < 4; ++i) {
        int u = bu + ty + i * 8;
        w1t[u * ND + bd + tx] = tile[tx][ty + i * 8];
    }
}

// ---- proj_h[b,u] = hidden[b,:] @ W2[:,u] + b2[u] ---------------------------
__global__ void k_projh(const float* __restrict__ hidden, const float* __restrict__ W2,
                        const float* __restrict__ b2, float* __restrict__ projh) {
    int b  = blockIdx.x >> 3;
    int uc = (blockIdx.x & 7) * 64;
    int ui = threadIdx.x & 63;
    int du = threadIdx.x >> 6;  // 0..3, splits D into 4 slabs of 128
    __shared__ float h[ND];
    __shared__ float part[4][64];
    for (int i = threadIdx.x; i < ND; i += 256) h[i] = hidden[b * ND + i];
    __syncthreads();
    int u = uc + ui;
    float acc = 0.f;
    int d0 = du * 128;
    #pragma unroll 8
    for (int d = 0; d < 128; ++d) acc += h[d0 + d] * W2[(d0 + d) * NU + u];
    part[du][ui] = acc;
    __syncthreads();
    if (threadIdx.x < 64) {
        projh[b * NU + u] = part[0][ui] + part[1][ui] + part[2][ui] + part[3][ui] + b2[u];
    }
}

// ---- fused: logits[bt] = bv + sum_u tanh(f@W1 + b1 + projh)[u] * V[u] ------
// block: 256 thr = 4 waves; tile 64 rows x 512 cols; wave w owns cols [w*128, +128)
__global__ __launch_bounds__(256, 2)
void k_logits(const float* __restrict__ feat, const u16* __restrict__ w1t,
              const float* __restrict__ b1, const float* __restrict__ projh,
              const float* __restrict__ V, const float* __restrict__ bv,
              float* __restrict__ logits) {
    __shared__ __align__(16) u16 aT[64 * APITCH];
    __shared__ float partial[4][64];

    const int row0 = blockIdx.x * 64;
    const int b    = row0 >> 11;          // 64 | 2048, so block is within one batch
    const int tid  = threadIdx.x;
    const int wave = tid >> 6, lane = tid & 63;
    const int quad = lane >> 4, col = lane & 15;

    float4v acc[4][8];
    #pragma unroll
    for (int mt = 0; mt < 4; ++mt)
        #pragma unroll
        for (int nt = 0; nt < 8; ++nt) acc[mt][nt] = (float4v)0.f;

    const int ar  = tid >> 3;   // staging row (round 0), rows 0..31
    const int ac4 = tid & 7;    // float4 column within 32-float k-slab
    const float* fbase = feat + (long)row0 * ND;

    for (int ks = 0; ks < 16; ++ks) {
        const int k0 = ks * 32;
        // stage A: 64 rows x 32 k, fp32 -> bf16, fully coalesced float4 loads
        #pragma unroll
        for (int rnd = 0; rnd < 2; ++rnd) {
            int r = ar + rnd * 32;
            float4v fv = *(const float4v*)(fbase + (long)r * ND + k0 + ac4 * 4);
            u16x4 us;
            us[0] = f2bf(fv[0]); us[1] = f2bf(fv[1]);
            us[2] = f2bf(fv[2]); us[3] = f2bf(fv[3]);
            *(u16x4*)(&aT[r * APITCH + ac4 * 4]) = us;
        }
        __syncthreads();

        bf16x8 af[4];
        #pragma unroll
        for (int mt = 0; mt < 4; ++mt)
            af[mt] = *(const bf16x8*)(&aT[(mt * 16 + col) * APITCH + quad * 8]);

        const u16* wb = w1t + ((wave * 128 + col) * ND) + k0 + quad * 8;
        #pragma unroll
        for (int nt = 0; nt < 8; ++nt) {
            bf16x8 bf = *(const bf16x8*)(wb + nt * 16 * ND);
            #pragma unroll
            for (int mt = 0; mt < 4; ++mt)
                acc[mt][nt] = __builtin_amdgcn_mfma_f32_16x16x32_bf16(af[mt], bf, acc[mt][nt], 0, 0, 0);
        }
        __syncthreads();
    }

    // epilogue: per lane, u's are fixed: u = wave*128 + nt*16 + col
    float b1v[8], phv[8], Vv[8];
    #pragma unroll
    for (int nt = 0; nt < 8; ++nt) {
        int u = wave * 128 + nt * 16 + col;
        b1v[nt] = b1[u];
        phv[nt] = projh[b * NU + u];
        Vv[nt]  = V[u];
    }
    float bvv = bv[0];

    #pragma unroll
    for (int mt = 0; mt < 4; ++mt) {
        #pragma unroll
        for (int rg = 0; rg < 4; ++rg) {
            float s = 0.f;
            #pragma unroll
            for (int nt = 0; nt < 8; ++nt) {
                float pv = acc[mt][nt][rg] + b1v[nt] + phv[nt];
                s += fast_tanh(pv) * Vv[nt];
            }
            // reduce over the 16 col-lanes of this quad
            s += __shfl_xor(s, 1);
            s += __shfl_xor(s, 2);
            s += __shfl_xor(s, 4);
            s += __shfl_xor(s, 8);
            if (col == 0) partial[wave][mt * 16 + quad * 4 + rg] = s;
        }
    }
    __syncthreads();
    if (tid < 64) {
        logits[row0 + tid] = partial[0][tid] + partial[1][tid] + partial[2][tid] + partial[3][tid] + bvv;
    }
}

// ---- softmax over T per batch ----------------------------------------------
__global__ void k_softmax(const float* __restrict__ logits, float* __restrict__ attn) {
    int b = blockIdx.x, tid = threadIdx.x;
    __shared__ float wm[4], ws[4];
    const float* lg = logits + b * NT;
    float lv[8];
    float m = -1e30f;
    #pragma unroll
    for (int i = 0; i < 8; ++i) { lv[i] = lg[tid + i * 256]; m = fmaxf(m, lv[i]); }
    for (int o = 1; o < 64; o <<= 1) m = fmaxf(m, __shfl_xor(m, o));
    if ((tid & 63) == 0) wm[tid >> 6] = m;
    __syncthreads();
    m = fmaxf(fmaxf(wm[0], wm[1]), fmaxf(wm[2], wm[3]));
    float ssum = 0.f, ev[8];
    #pragma unroll
    for (int i = 0; i < 8; ++i) { ev[i] = __expf(lv[i] - m); ssum += ev[i]; }
    for (int o = 1; o < 64; o <<= 1) ssum += __shfl_xor(ssum, o);
    if ((tid & 63) == 0) ws[tid >> 6] = ssum;
    __syncthreads();
    float inv = 1.f / (ws[0] + ws[1] + ws[2] + ws[3]);
    #pragma unroll
    for (int i = 0; i < 8; ++i) attn[b * NT + tid + i * 256] = ev[i] * inv;
}

// ---- context[b,d] = sum_t attn[b,t] * feat[b,t,d] --------------------------
__global__ void k_context(const float* __restrict__ feat, const float* __restrict__ attn,
                          float* __restrict__ ctx) {
    int blk = blockIdx.x;           // 32 b * 2 dhalf * 16 tchunk
    int b  = blk >> 5;
    int dh = (blk >> 4) & 1;
    int tc = blk & 15;
    int d  = dh * 256 + threadIdx.x;
    const float* fb = feat + ((long)b * NT + tc * 128) * ND + d;
    const float* ab = attn + b * NT + tc * 128;
    float acc = 0.f;
    #pragma unroll 8
    for (int t = 0; t < 128; ++t) acc += ab[t] * fb[(long)t * ND];
    atomicAdd(&ctx[b * ND + d], acc);
}

extern "C" void kernel_launch(void* const* d_in, const int* in_sizes, int n_in,
                              void* d_out, int out_size, void* d_ws, size_t ws_size,
                              hipStream_t stream) {
    const float* feat   = (const float*)d_in[0];
    const float* hidden = (const float*)d_in[1];
    const float* W1     = (const float*)d_in[2];
    const float* b1     = (const float*)d_in[3];
    const float* W2     = (const float*)d_in[4];
    const float* b2     = (const float*)d_in[5];
    const float* V      = (const float*)d_in[6];
    const float* bv     = (const float*)d_in[7];

    float* out_ctx  = (float*)d_out;            // [32,512] = 16384 floats
    float* out_attn = (float*)d_out + NB * ND;  // [32,2048,1] = 65536 floats

    u16*   w1t    = (u16*)d_ws;                                          // 512 KB
    float* projh  = (float*)((char*)d_ws + 512 * 1024);                  // 64 KB
    float* logits = (float*)((char*)d_ws + 512 * 1024 + 64 * 1024);      // 256 KB

    hipMemsetAsync(out_ctx, 0, NB * ND * sizeof(float), stream);
    k_w1t    <<<256, 256, 0, stream>>>(W1, w1t);
    k_projh  <<<256, 256, 0, stream>>>(hidden, W2, b2, projh);
    k_logits <<<1024, 256, 0, stream>>>(feat, w1t, b1, projh, V, bv, logits);
    k_softmax<<<NB, 256, 0, stream>>>(logits, out_attn);
    k_context<<<1024, 256, 0, stream>>>(feat, out_attn, out_ctx);
}

// Round 2
// 301.082 us; speedup vs baseline: 1.0400x; 1.0400x over previous
//
#include <hip/hip_runtime.h>
#include <hip/hip_bf16.h>

typedef __bf16 bf16x8 __attribute__((ext_vector_type(8)));
typedef float  float4v __attribute__((ext_vector_type(4)));
typedef unsigned short u16;
typedef u16 u16x8 __attribute__((ext_vector_type(8)));

#define NB 32
#define NT 2048
#define ND 512
#define NU 512
// A-tile pitch in u16: 264 -> 528 B row stride; 528/4=132 == 4 (mod 8) banks,
// so 16-row fragment reads land on 8 distinct 4-bank starts (2-way = free),
// and staging stores are 16B lane-contiguous within a row (conflict-free).
#define AP 264

__device__ __forceinline__ u16 f2bf(float f) {
    union { float f; unsigned u; } v; v.f = f;
    unsigned u = v.u;
    return (u16)((u + 0x7fffu + ((u >> 16) & 1u)) >> 16);  // RNE
}

__device__ __forceinline__ float fast_tanh(float x) {
    float e = __expf(-2.f * x);
    return 2.f / (1.f + e) - 1.f;
}

// ---- fused setup: blocks 0..255 transpose W1->bf16 W1^T; 256..511 projh ----
__global__ void k_setup(const float* __restrict__ W1, u16* __restrict__ w1t,
                        const float* __restrict__ hidden, const float* __restrict__ W2,
                        const float* __restrict__ b2, float* __restrict__ projh) {
    __shared__ u16 tile[32][33];
    __shared__ float h[ND];
    __shared__ float part[4][64];
    if (blockIdx.x < 256) {
        int bd = (blockIdx.x & 15) * 32;
        int bu = (blockIdx.x >> 4) * 32;
        int tx = threadIdx.x & 31, ty = threadIdx.x >> 5;
        #pragma unroll
        for (int i = 0; i < 4; ++i)
            tile[ty + i * 8][tx] = f2bf(W1[(bd + ty + i * 8) * NU + bu + tx]);
        __syncthreads();
        #pragma unroll
        for (int i = 0; i < 4; ++i)
            w1t[(bu + ty + i * 8) * ND + bd + tx] = tile[tx][ty + i * 8];
    } else {
        int blk = blockIdx.x - 256;
        int b  = blk >> 3;
        int uc = (blk & 7) * 64;
        int ui = threadIdx.x & 63;
        int du = threadIdx.x >> 6;
        for (int i = threadIdx.x; i < ND; i += 256) h[i] = hidden[b * ND + i];
        __syncthreads();
        int u = uc + ui;
        float acc = 0.f;
        int d0 = du * 128;
        #pragma unroll 8
        for (int d = 0; d < 128; ++d) acc += h[d0 + d] * W2[(d0 + d) * NU + u];
        part[du][ui] = acc;
        __syncthreads();
        if (threadIdx.x < 64)
            projh[b * NU + u] = part[0][ui] + part[1][ui] + part[2][ui] + part[3][ui] + b2[u];
    }
}

// ---- fused: logits[bt] = bv + sum_u tanh(f@W1 + b1 + projh)[u] * V[u] ------
// 256 thr = 4 waves; tile 64 rows x 512 cols; wave w owns cols [w*128,+128).
// K staged in 2 phases of 256 (33KB LDS) -> 4 barriers total, long MFMA runs.
__global__ __launch_bounds__(256, 2)
void k_logits(const float* __restrict__ feat, const u16* __restrict__ w1t,
              const float* __restrict__ b1, const float* __restrict__ projh,
              const float* __restrict__ V, const float* __restrict__ bv,
              float* __restrict__ logits) {
    __shared__ __align__(16) u16 aT[64 * AP];
    __shared__ float partial[4][64];

    const int row0 = blockIdx.x * 64;
    const int b    = row0 >> 11;
    const int tid  = threadIdx.x;
    const int wave = tid >> 6, lane = tid & 63;
    const int quad = lane >> 4, col = lane & 15;

    float4v acc[4][8];
    #pragma unroll
    for (int mt = 0; mt < 4; ++mt)
        #pragma unroll
        for (int nt = 0; nt < 8; ++nt) acc[mt][nt] = (float4v)0.f;

    // staging map: thread t covers granule g=t&31 (8 floats) of rows (t>>5)+8i
    const int sg = tid & 31;
    const int sr = tid >> 5;
    const float* fbase = feat + (long)row0 * ND;

    #pragma unroll
    for (int h = 0; h < 2; ++h) {
        const int k0 = h * 256;
        // stage 64 rows x 256 k: 16 independent float4 loads per thread
        #pragma unroll
        for (int i = 0; i < 8; ++i) {
            int r = sr + i * 8;
            const float* p = fbase + (long)r * ND + k0 + sg * 8;
            float4v f0 = *(const float4v*)(p);
            float4v f1 = *(const float4v*)(p + 4);
            u16x8 us;
            us[0] = f2bf(f0[0]); us[1] = f2bf(f0[1]); us[2] = f2bf(f0[2]); us[3] = f2bf(f0[3]);
            us[4] = f2bf(f1[0]); us[5] = f2bf(f1[1]); us[6] = f2bf(f1[2]); us[7] = f2bf(f1[3]);
            *(u16x8*)(&aT[r * AP + sg * 8]) = us;
        }
        __syncthreads();

        #pragma unroll
        for (int ks = 0; ks < 8; ++ks) {
            bf16x8 af[4];
            #pragma unroll
            for (int mt = 0; mt < 4; ++mt)
                af[mt] = *(const bf16x8*)(&aT[(mt * 16 + col) * AP + (ks * 4 + quad) * 8]);

            const u16* wb = w1t + ((wave * 128 + col) * ND) + k0 + ks * 32 + quad * 8;
            #pragma unroll
            for (int nt = 0; nt < 8; ++nt) {
                bf16x8 bf = *(const bf16x8*)(wb + nt * 16 * ND);
                #pragma unroll
                for (int mt = 0; mt < 4; ++mt)
                    acc[mt][nt] = __builtin_amdgcn_mfma_f32_16x16x32_bf16(af[mt], bf, acc[mt][nt], 0, 0, 0);
            }
        }
        __syncthreads();
    }

    // epilogue: u = wave*128 + nt*16 + col
    float b1v[8], phv[8], Vv[8];
    #pragma unroll
    for (int nt = 0; nt < 8; ++nt) {
        int u = wave * 128 + nt * 16 + col;
        b1v[nt] = b1[u];
        phv[nt] = projh[b * NU + u];
        Vv[nt]  = V[u];
    }
    float bvv = bv[0];

    #pragma unroll
    for (int mt = 0; mt < 4; ++mt) {
        #pragma unroll
        for (int rg = 0; rg < 4; ++rg) {
            float s = 0.f;
            #pragma unroll
            for (int nt = 0; nt < 8; ++nt) {
                float pv = acc[mt][nt][rg] + b1v[nt] + phv[nt];
                s += fast_tanh(pv) * Vv[nt];
            }
            s += __shfl_xor(s, 1);
            s += __shfl_xor(s, 2);
            s += __shfl_xor(s, 4);
            s += __shfl_xor(s, 8);
            if (col == 0) partial[wave][mt * 16 + quad * 4 + rg] = s;
        }
    }
    __syncthreads();
    if (tid < 64)
        logits[row0 + tid] = partial[0][tid] + partial[1][tid] + partial[2][tid] + partial[3][tid] + bvv;
}

// ---- softmax over T per batch ----------------------------------------------
__global__ void k_softmax(const float* __restrict__ logits, float* __restrict__ attn) {
    int b = blockIdx.x, tid = threadIdx.x;
    __shared__ float wm[4], ws[4];
    const float* lg = logits + b * NT;
    float lv[8];
    float m = -1e30f;
    #pragma unroll
    for (int i = 0; i < 8; ++i) { lv[i] = lg[tid + i * 256]; m = fmaxf(m, lv[i]); }
    for (int o = 1; o < 64; o <<= 1) m = fmaxf(m, __shfl_xor(m, o));
    if ((tid & 63) == 0) wm[tid >> 6] = m;
    __syncthreads();
    m = fmaxf(fmaxf(wm[0], wm[1]), fmaxf(wm[2], wm[3]));
    float ssum = 0.f, ev[8];
    #pragma unroll
    for (int i = 0; i < 8; ++i) { ev[i] = __expf(lv[i] - m); ssum += ev[i]; }
    for (int o = 1; o < 64; o <<= 1) ssum += __shfl_xor(ssum, o);
    if ((tid & 63) == 0) ws[tid >> 6] = ssum;
    __syncthreads();
    float inv = 1.f / (ws[0] + ws[1] + ws[2] + ws[3]);
    #pragma unroll
    for (int i = 0; i < 8; ++i) attn[b * NT + tid + i * 256] = ev[i] * inv;
}

// ---- context[b,d] = sum_t attn[b,t] * feat[b,t,d] --------------------------
__global__ void k_context(const float* __restrict__ feat, const float* __restrict__ attn,
                          float* __restrict__ ctx) {
    int blk = blockIdx.x;           // 32 b * 2 dhalf * 16 tchunk
    int b  = blk >> 5;
    int dh = (blk >> 4) & 1;
    int tc = blk & 15;
    int d  = dh * 256 + threadIdx.x;
    const float* fb = feat + ((long)b * NT + tc * 128) * ND + d;
    const float* ab = attn + b * NT + tc * 128;
    float acc = 0.f;
    #pragma unroll 16
    for (int t = 0; t < 128; ++t) acc += ab[t] * fb[(long)t * ND];
    atomicAdd(&ctx[b * ND + d], acc);
}

extern "C" void kernel_launch(void* const* d_in, const int* in_sizes, int n_in,
                              void* d_out, int out_size, void* d_ws, size_t ws_size,
                              hipStream_t stream) {
    const float* feat   = (const float*)d_in[0];
    const float* hidden = (const float*)d_in[1];
    const float* W1     = (const float*)d_in[2];
    const float* b1     = (const float*)d_in[3];
    const float* W2     = (const float*)d_in[4];
    const float* b2     = (const float*)d_in[5];
    const float* V      = (const float*)d_in[6];
    const float* bv     = (const float*)d_in[7];

    float* out_ctx  = (float*)d_out;            // [32,512]
    float* out_attn = (float*)d_out + NB * ND;  // [32,2048,1]

    u16*   w1t    = (u16*)d_ws;                                          // 512 KB
    float* projh  = (float*)((char*)d_ws + 512 * 1024);                  // 64 KB
    float* logits = (float*)((char*)d_ws + 512 * 1024 + 64 * 1024);      // 256 KB

    hipMemsetAsync(out_ctx, 0, NB * ND * sizeof(float), stream);
    k_setup  <<<512, 256, 0, stream>>>(W1, w1t, hidden, W2, b2, projh);
    k_logits <<<1024, 256, 0, stream>>>(feat, w1t, b1, projh, V, bv, logits);
    k_softmax<<<NB, 256, 0, stream>>>(logits, out_attn);
    k_context<<<1024, 256, 0, stream>>>(feat, out_attn, out_ctx);
}

// Round 3
// 266.812 us; speedup vs baseline: 1.1736x; 1.1284x over previous
//
#include <hip/hip_runtime.h>
#include <hip/hip_bf16.h>

typedef __bf16 bf16x8 __attribute__((ext_vector_type(8)));
typedef float  float4v __attribute__((ext_vector_type(4)));
typedef unsigned short u16;
typedef u16 u16x8 __attribute__((ext_vector_type(8)));

#define NB 32
#define NT 2048
#define ND 512
#define NU 512
#define BK 64        // K per phase; 8 phases

__device__ __forceinline__ u16 f2bf(float f) {
    union { float f; unsigned u; } v; v.f = f;
    unsigned u = v.u;
    return (u16)((u + 0x7fffu + ((u >> 16) & 1u)) >> 16);  // RNE
}

// 8 fp32 -> 8 bf16 via packed converts
__device__ __forceinline__ u16x8 cvt8(float4v a, float4v b) {
    union { __hip_bfloat162 h[4]; u16x8 v; } u;
    u.h[0] = __float22bfloat162_rn(make_float2(a[0], a[1]));
    u.h[1] = __float22bfloat162_rn(make_float2(a[2], a[3]));
    u.h[2] = __float22bfloat162_rn(make_float2(b[0], b[1]));
    u.h[3] = __float22bfloat162_rn(make_float2(b[2], b[3]));
    return u.v;
}

__device__ __forceinline__ float fast_tanh(float x) {
    float e = __expf(-2.f * x);
    return 2.f / (1.f + e) - 1.f;
}

// ---- setup: W1->bf16 W1^T, projh, and zero logits/ctx (folds the memsets) --
__global__ void k_setup(const float* __restrict__ W1, u16* __restrict__ w1t,
                        const float* __restrict__ hidden, const float* __restrict__ W2,
                        const float* __restrict__ b2, float* __restrict__ projh,
                        float* __restrict__ logits, float* __restrict__ ctx) {
    __shared__ u16 tile[32][33];
    __shared__ float h[ND];
    __shared__ float part[4][64];
    // zeroing: 512 blocks cover logits (65536) and ctx (16384)
    if (threadIdx.x < 128) logits[blockIdx.x * 128 + threadIdx.x] = 0.f;
    else if (threadIdx.x < 160) ctx[blockIdx.x * 32 + (threadIdx.x - 128)] = 0.f;

    if (blockIdx.x < 256) {
        int bd = (blockIdx.x & 15) * 32;
        int bu = (blockIdx.x >> 4) * 32;
        int tx = threadIdx.x & 31, ty = threadIdx.x >> 5;
        #pragma unroll
        for (int i = 0; i < 4; ++i)
            tile[ty + i * 8][tx] = f2bf(W1[(bd + ty + i * 8) * NU + bu + tx]);
        __syncthreads();
        #pragma unroll
        for (int i = 0; i < 4; ++i)
            w1t[(bu + ty + i * 8) * ND + bd + tx] = tile[tx][ty + i * 8];
    } else {
        int blk = blockIdx.x - 256;
        int b  = blk >> 3;
        int uc = (blk & 7) * 64;
        int ui = threadIdx.x & 63;
        int du = threadIdx.x >> 6;
        for (int i = threadIdx.x; i < ND; i += 256) h[i] = hidden[b * ND + i];
        __syncthreads();
        int u = uc + ui;
        float acc = 0.f;
        int d0 = du * 128;
        #pragma unroll 8
        for (int d = 0; d < 128; ++d) acc += h[d0 + d] * W2[(d0 + d) * NU + u];
        part[du][ui] = acc;
        __syncthreads();
        if (threadIdx.x < 64)
            projh[b * NU + u] = part[0][ui] + part[1][ui] + part[2][ui] + part[3][ui] + b2[u];
    }
}

// ---- logits partial: block = 64 rows x 256 U-cols, full K=512 --------------
// 4 waves, wave owns 64 rows x 64 cols (mt=4, nt=4, acc=64 VGPR).
// BK=64 phases: A fp32->bf16 via regs+ds_write, B bf16 via global_load_lds.
// Both LDS tiles use 128B rows with XOR-of-row k-chunk swizzle -> 2-way reads.
__global__ __launch_bounds__(256, 4)
void k_logits(const float* __restrict__ feat, const u16* __restrict__ w1t,
              const float* __restrict__ b1, const float* __restrict__ projh,
              const float* __restrict__ V, float* __restrict__ logits) {
    __shared__ __align__(16) u16 aT[64 * BK];    // 8 KB
    __shared__ __align__(16) u16 bT[256 * BK];   // 32 KB  (total 40 KB -> 4 blocks/CU)

    const int mtile = blockIdx.x & 1023;
    const int utile = blockIdx.x >> 10;          // 0..1
    const int row0  = mtile * 64;
    const int uc    = utile * 256;
    const int b     = row0 >> 11;
    const int tid   = threadIdx.x;
    const int wave  = tid >> 6, lane = tid & 63;
    const int quad  = lane >> 4, col = lane & 15;

    float4v acc[4][4];
    #pragma unroll
    for (int mt = 0; mt < 4; ++mt)
        #pragma unroll
        for (int nt = 0; nt < 4; ++nt) acc[mt][nt] = (float4v)0.f;

    const float* fbase = feat + (long)row0 * ND;
    const u16*   wbase = w1t + uc * ND;

    for (int p = 0; p < 8; ++p) {
        const int k0 = p * BK;
        // ---- stage A: 64 rows x 64 k fp32 -> bf16. slots: (row, chunk of 8)
        #pragma unroll
        for (int i = 0; i < 2; ++i) {
            int s = tid + i * 256;
            int r = s >> 3, c = s & 7;
            const float* gp = fbase + r * ND + k0 + c * 8;
            float4v f0 = *(const float4v*)gp;
            float4v f1 = *(const float4v*)(gp + 4);
            int wc = c ^ (r & 7);
            *(u16x8*)(&aT[r * BK + wc * 8]) = cvt8(f0, f1);
        }
        // ---- stage B: 256 rows x 64 k bf16 via global_load_lds (16B/lane)
        #pragma unroll
        for (int j = 0; j < 8; ++j) {
            int s = j * 256 + tid;           // slot: LDS dst = bT + s*16B
            int r = s >> 3;
            int gc = (s & 7) ^ (r & 7);      // swizzled global chunk
            const u16* gp = wbase + r * ND + k0 + gc * 8;
            u16* lp = &bT[(j * 256 + wave * 64) * 8];   // wave-uniform base
            __builtin_amdgcn_global_load_lds(
                (const __attribute__((address_space(1))) unsigned int*)gp,
                (__attribute__((address_space(3))) unsigned int*)lp, 16, 0, 0);
        }
        __syncthreads();

        #pragma unroll
        for (int ks = 0; ks < 2; ++ks) {
            bf16x8 af[4], bf[4];
            #pragma unroll
            for (int mt = 0; mt < 4; ++mt) {
                int ra = mt * 16 + col;
                af[mt] = *(const bf16x8*)(&aT[ra * BK + (((ks * 4 + quad) ^ (ra & 7)) * 8)]);
            }
            #pragma unroll
            for (int nt = 0; nt < 4; ++nt) {
                int rb = wave * 64 + nt * 16 + col;
                bf[nt] = *(const bf16x8*)(&bT[rb * BK + (((ks * 4 + quad) ^ (rb & 7)) * 8)]);
            }
            #pragma unroll
            for (int nt = 0; nt < 4; ++nt)
                #pragma unroll
                for (int mt = 0; mt < 4; ++mt)
                    acc[mt][nt] = __builtin_amdgcn_mfma_f32_16x16x32_bf16(af[mt], bf[nt], acc[mt][nt], 0, 0, 0);
        }
        __syncthreads();
    }

    // ---- epilogue: u = uc + wave*64 + nt*16 + col; partial logit per row
    float b1v[4], phv[4], Vv[4];
    #pragma unroll
    for (int nt = 0; nt < 4; ++nt) {
        int u = uc + wave * 64 + nt * 16 + col;
        b1v[nt] = b1[u];
        phv[nt] = projh[b * NU + u];
        Vv[nt]  = V[u];
    }

    float (*partial)[64] = (float(*)[64])aT;   // reuse A-tile LDS (post-barrier)
    #pragma unroll
    for (int mt = 0; mt < 4; ++mt) {
        #pragma unroll
        for (int rg = 0; rg < 4; ++rg) {
            float s = 0.f;
            #pragma unroll
            for (int nt = 0; nt < 4; ++nt) {
                float pv = acc[mt][nt][rg] + b1v[nt] + phv[nt];
                s += fast_tanh(pv) * Vv[nt];
            }
            s += __shfl_xor(s, 1);
            s += __shfl_xor(s, 2);
            s += __shfl_xor(s, 4);
            s += __shfl_xor(s, 8);
            if (col == 0) partial[wave][mt * 16 + quad * 4 + rg] = s;
        }
    }
    __syncthreads();
    if (tid < 64) {
        float v = partial[0][tid] + partial[1][tid] + partial[2][tid] + partial[3][tid];
        atomicAdd(&logits[row0 + tid], v);
    }
}

// ---- softmax over T per batch (bv dropped: softmax is shift-invariant) -----
__global__ void k_softmax(const float* __restrict__ logits, float* __restrict__ attn) {
    int b = blockIdx.x, tid = threadIdx.x;   // 1024 threads
    __shared__ float wm[16], ws[16];
    const float* lg = logits + b * NT;
    float lv[2];
    float m = -1e30f;
    #pragma unroll
    for (int i = 0; i < 2; ++i) { lv[i] = lg[tid + i * 1024]; m = fmaxf(m, lv[i]); }
    for (int o = 1; o < 64; o <<= 1) m = fmaxf(m, __shfl_xor(m, o));
    if ((tid & 63) == 0) wm[tid >> 6] = m;
    __syncthreads();
    #pragma unroll
    for (int i = 0; i < 16; ++i) m = fmaxf(m, wm[i]);
    float ssum = 0.f, ev[2];
    #pragma unroll
    for (int i = 0; i < 2; ++i) { ev[i] = __expf(lv[i] - m); ssum += ev[i]; }
    for (int o = 1; o < 64; o <<= 1) ssum += __shfl_xor(ssum, o);
    if ((tid & 63) == 0) ws[tid >> 6] = ssum;
    __syncthreads();
    float tot = 0.f;
    #pragma unroll
    for (int i = 0; i < 16; ++i) tot += ws[i];
    float inv = 1.f / tot;
    #pragma unroll
    for (int i = 0; i < 2; ++i) attn[b * NT + tid + i * 1024] = ev[i] * inv;
}

// ---- context[b,d] = sum_t attn[b,t] * feat[b,t,d] --------------------------
// grid 1024 = 32 b x 32 t-chunks of 64; thread owns float2 of d.
__global__ void k_context(const float* __restrict__ feat, const float* __restrict__ attn,
                          float* __restrict__ ctx) {
    int b  = blockIdx.x >> 5;
    int tc = blockIdx.x & 31;
    const float* fb = feat + ((long)b * NT + tc * 64) * ND + threadIdx.x * 2;
    const float* ab = attn + b * NT + tc * 64;
    float ax = 0.f, ay = 0.f;
    #pragma unroll 16
    for (int t = 0; t < 64; ++t) {
        float a = ab[t];
        float2 f = *(const float2*)(fb + (long)t * ND);
        ax += a * f.x; ay += a * f.y;
    }
    atomicAdd(&ctx[b * ND + threadIdx.x * 2],     ax);
    atomicAdd(&ctx[b * ND + threadIdx.x * 2 + 1], ay);
}

extern "C" void kernel_launch(void* const* d_in, const int* in_sizes, int n_in,
                              void* d_out, int out_size, void* d_ws, size_t ws_size,
                              hipStream_t stream) {
    const float* feat   = (const float*)d_in[0];
    const float* hidden = (const float*)d_in[1];
    const float* W1     = (const float*)d_in[2];
    const float* b1     = (const float*)d_in[3];
    const float* W2     = (const float*)d_in[4];
    const float* b2     = (const float*)d_in[5];
    const float* V      = (const float*)d_in[6];
    // d_in[7] = bv: unused — softmax(x + bv) == softmax(x)

    float* out_ctx  = (float*)d_out;            // [32,512]
    float* out_attn = (float*)d_out + NB * ND;  // [32,2048,1]

    u16*   w1t    = (u16*)d_ws;                                          // 512 KB
    float* projh  = (float*)((char*)d_ws + 512 * 1024);                  // 64 KB
    float* logits = (float*)((char*)d_ws + 512 * 1024 + 64 * 1024);      // 256 KB

    k_setup  <<<512, 256, 0, stream>>>(W1, w1t, hidden, W2, b2, projh, logits, out_ctx);
    k_logits <<<2048, 256, 0, stream>>>(feat, w1t, b1, projh, V, logits);
    k_softmax<<<NB, 1024, 0, stream>>>(logits, out_attn);
    k_context<<<1024, 256, 0, stream>>>(feat, out_attn, out_ctx);
}